// Round 9
// baseline (269.095 us; speedup 1.0000x reference)
//
#include <hip/hip_runtime.h>
#include <math.h>

#define TT   32
#define NB   2048
#define SDIM 256
#define ADIM 64
#define LDIM 128
#define HID  750
#define KP   768    // padded neuron count (k-dim of layer-2 GEMMs)
#define KW   24     // KP/32 words per batch row (bit layout [b][kw][t])
#define EIN  320    // SDIM + ADIM
#define DIN  384    // SDIM + LDIM
#define NSTEP 12    // KP / 64

typedef float    f32x4 __attribute__((ext_vector_type(4)));
typedef int      i32x4 __attribute__((ext_vector_type(4)));
typedef unsigned u32x4 __attribute__((ext_vector_type(4)));

// v_mfma_f32_16x16x32_bf16: A row=lane&15, k=(lane>>4)*8+e; B col=lane&15;
// C/D col=lane&15, row=(lane>>4)*4+reg.  (verified R2..R7)
__device__ __forceinline__ f32x4 mfma16(u32x4 a, u32x4 b, f32x4 c) {
    asm("v_mfma_f32_16x16x32_bf16 %0, %1, %2, %0" : "+v"(c) : "v"(a), "v"(b));
    return c;
}
// v_mfma_i32_16x16x64_i8: A row=lane&15, k=(lane>>4)*16 + reg*4 + byte. (verified R4..R7)
__device__ __forceinline__ i32x4 mfma_i8(u32x4 a, u32x4 b, i32x4 c) {
    asm("v_mfma_i32_16x16x64_i8 %0, %1, %2, %0" : "+v"(c) : "v"(a), "v"(b));
    return c;
}

__device__ __forceinline__ void gload_lds16(void* lds, const void* g) {
    __builtin_amdgcn_global_load_lds(
        (const __attribute__((address_space(1))) unsigned int*)g,
        (__attribute__((address_space(3))) unsigned int*)lds, 16, 0, 0);
}

// round-to-nearest-even bf16 hi/lo split (verified R2..R7)
__device__ __forceinline__ void bfsplit(float v, unsigned& hb, unsigned& lb) {
    unsigned u = __float_as_uint(v);
    hb = (u + 0x7FFFu + ((u >> 16) & 1u)) >> 16;
    float res = v - __uint_as_float(hb << 16);
    unsigned u2 = __float_as_uint(res);
    lb = (u2 + 0x7FFFu + ((u2 >> 16) & 1u)) >> 16;
}

// ---------------------------------------------------------------------------
// Merged weight-quant kernel: all five i8 2-limb splits in one launch.
// Layout per (o_blk,k_blk) 4KB block: off = kg*1024 + (o&63)*16 + (k&15).
// ---------------------------------------------------------------------------
#define I8_E1 589824          // W2   (768 rows)
#define I8_E2 1179648         // Wd2  (768 rows)
#define I8_E3 1277952         // Wm   (128 rows)
#define I8_E4 1376256         // Wls  (128 rows)
#define I8_E5 1425408         // Wd3  (64 rows)
__global__ void wsplit_i8_all(const float* __restrict__ W2,
                              const float* __restrict__ Wd2,
                              const float* __restrict__ Wm,
                              const float* __restrict__ Wls,
                              const float* __restrict__ Wd3,
                              char* __restrict__ W2h,  char* __restrict__ W2l,
                              char* __restrict__ Wd2h, char* __restrict__ Wd2l,
                              char* __restrict__ WmlsH, char* __restrict__ WmlsL,
                              char* __restrict__ Wu3h, char* __restrict__ Wu3l) {
    int i = blockIdx.x * blockDim.x + threadIdx.x;
    if (i >= I8_E5) return;
    const float* src; char* dh; char* dl; int rvalid, o_base;
    if (i < I8_E1)      { src = W2;  dh = W2h;  dl = W2l;  rvalid = HID;  o_base = 0; }
    else if (i < I8_E2) { i -= I8_E1; src = Wd2; dh = Wd2h; dl = Wd2l; rvalid = HID;  o_base = 0; }
    else if (i < I8_E3) { i -= I8_E2; src = Wm;  dh = WmlsH; dl = WmlsL; rvalid = LDIM; o_base = 0; }
    else if (i < I8_E4) { i -= I8_E3; src = Wls; dh = WmlsH; dl = WmlsL; rvalid = LDIM; o_base = 128; }
    else                { i -= I8_E4; src = Wd3; dh = Wu3h; dl = Wu3l; rvalid = ADIM; o_base = 0; }
    int r = i / KP, k = i % KP;
    float v = (r < rvalid && k < HID) ? src[r * HID + k] : 0.f;
    int q = (int)rintf(v * 524288.f);
    int lo = (q << 24) >> 24;           // sext low byte
    int hi = (q - lo) >> 8;
    int o = o_base + r;
    size_t di = (size_t)((o >> 6) * NSTEP + (k >> 6)) * 4096
              + ((k >> 4) & 3) * 1024 + (o & 63) * 16 + (k & 15);
    dh[di] = (char)hi;
    dl[di] = (char)lo;
}

// ---------------------------------------------------------------------------
// Merged layer-1 weight split (W1 KS=5, Wd1 KS=6), bf16 hi/lo packed per
// (nb,ks64) 8KB block: elem = (kc*4+kg)*512 + (o&63)*8 + (k&7).
// ---------------------------------------------------------------------------
#define BF_E1 245760          // W1 (KP x EIN)
#define BF_E2 540672          // Wd1 (KP x DIN)
__global__ void wsplit_bf_all(const float* __restrict__ W1,
                              const float* __restrict__ Wd1,
                              unsigned short* __restrict__ W1h,
                              unsigned short* __restrict__ W1l,
                              unsigned short* __restrict__ Wd1h,
                              unsigned short* __restrict__ Wd1l) {
    int i = blockIdx.x * blockDim.x + threadIdx.x;
    if (i >= BF_E2) return;
    const float* src; unsigned short* dh; unsigned short* dl; int K, KS;
    if (i < BF_E1) { src = W1; dh = W1h; dl = W1l; K = EIN; KS = 5; }
    else { i -= BF_E1; src = Wd1; dh = Wd1h; dl = Wd1l; K = DIN; KS = 6; }
    int r = i / K, k = i % K;
    float v = (r < HID) ? src[r * K + k] : 0.f;
    unsigned hb, lb;
    bfsplit(v, hb, lb);
    size_t di = ((size_t)((r >> 6) * KS + (k >> 6)) * 8
               + ((k >> 5) & 1) * 4 + ((k >> 3) & 3)) * 512 + (r & 63) * 8 + (k & 7);
    dh[di] = (unsigned short)hb;
    dl[di] = (unsigned short)lb;
}

// ---------------------------------------------------------------------------
// Fused encoder concat + bf16 hi/lo split, A layout idx = ((k>>3)*NB + b)*8 + (k&7)
// ---------------------------------------------------------------------------
__global__ void concat_xsplit_enc(const float* __restrict__ state,
                                  const float* __restrict__ action,
                                  unsigned short* __restrict__ Xh,
                                  unsigned short* __restrict__ Xl) {
    int t = blockIdx.x * blockDim.x + threadIdx.x;
    if (t >= NB * (EIN / 8)) return;
    int b = t & (NB - 1), c8 = t >> 11;
    float vals[8];
    if (c8 < SDIM / 8) {
        const float* src = state + (size_t)b * SDIM + c8 * 8;
#pragma unroll
        for (int j = 0; j < 8; ++j) vals[j] = src[j];
    } else {
        const float* src = action + (size_t)b * ADIM + (c8 * 8 - SDIM);
#pragma unroll
        for (int j = 0; j < 8; ++j) vals[j] = src[j];
    }
    unsigned hs[8], ls[8];
#pragma unroll
    for (int j = 0; j < 8; ++j) bfsplit(vals[j], hs[j], ls[j]);
    u32x4 ph, pl;
#pragma unroll
    for (int j = 0; j < 4; ++j) {
        ph[j] = hs[2 * j] | (hs[2 * j + 1] << 16);
        pl[j] = ls[2 * j] | (ls[2 * j + 1] << 16);
    }
    *(u32x4*)(Xh + (size_t)t * 8) = ph;
    *(u32x4*)(Xl + (size_t)t * 8) = pl;
}

// ---------------------------------------------------------------------------
// Fused latent + decoder concat + split.
// ---------------------------------------------------------------------------
__global__ void latent_xsplit(const float* __restrict__ mean_ws,
                              const float* __restrict__ ls_ws,
                              const float* __restrict__ eps,
                              const float* __restrict__ state,
                              float* __restrict__ out,
                              unsigned short* __restrict__ Xh,
                              unsigned short* __restrict__ Xl) {
    int t = blockIdx.x * blockDim.x + threadIdx.x;
    if (t >= NB * (DIN / 8)) return;
    int b = t & (NB - 1), c8 = t >> 11;
    float vals[8];
    if (c8 < SDIM / 8) {
        const float* src = state + (size_t)b * SDIM + c8 * 8;
#pragma unroll
        for (int j = 0; j < 8; ++j) vals[j] = src[j];
    } else {
        int o0 = c8 * 8 - SDIM;
#pragma unroll
        for (int j = 0; j < 8; ++j) {
            int o = o0 + j;
            float m = mean_ws[(size_t)b * LDIM + o];
            float l = ls_ws[(size_t)b * LDIM + o];
            l = fminf(fmaxf(l, -4.0f), 15.0f);
            float s = expf(l);
            vals[j] = m + s * eps[(size_t)b * LDIM + o];
            out[NB * ADIM + (size_t)b * LDIM + o] = m;
            out[NB * ADIM + NB * LDIM + (size_t)b * LDIM + o] = s;
        }
    }
    unsigned hs[8], ls[8];
#pragma unroll
    for (int j = 0; j < 8; ++j) bfsplit(vals[j], hs[j], ls[j]);
    u32x4 ph, pl;
#pragma unroll
    for (int j = 0; j < 4; ++j) {
        ph[j] = hs[2 * j] | (hs[2 * j + 1] << 16);
        pl[j] = ls[2 * j] | (ls[2 * j + 1] << 16);
    }
    *(u32x4*)(Xh + (size_t)t * 8) = ph;
    *(u32x4*)(Xl + (size_t)t * 8) = pl;
}

// ---------------------------------------------------------------------------
// Layer-1 (R7-verbatim, proven): bf16 3-product MFMA GEMM + const-input LIF
// + ballot bit-transpose -> bitsT[b][kw][t]. Per-step vmcnt(0) full drain
// (order-robust by construction). Block: 4 waves, M=128, N=64.
// ---------------------------------------------------------------------------
template<int KS>
__global__ __launch_bounds__(256)
void lif1(const unsigned short* __restrict__ Ah,
          const unsigned short* __restrict__ Al,
          const unsigned short* __restrict__ Wh,
          const unsigned short* __restrict__ Wl,
          const float* __restrict__ bias,
          unsigned* __restrict__ obitsT) {
    __shared__ __align__(16) char smraw[32768];  // 2x16KB bufs | epi Sb[128][64] u32
    const int tid = threadIdx.x, wave = tid >> 6, l = tid & 63;
    const int kg = l >> 4, li = l & 15;
    const int nb = blockIdx.x, n0 = nb * 64, mb = blockIdx.y;
    const int r0 = mb * 128 + wave * 32;
    f32x4 acc[2][4] = {};

    auto stage = [&](int buf, int step) {
        const char* sH = (const char*)(Wh + (size_t)(nb * KS + step) * 4096);
        const char* sL = (const char*)(Wl + (size_t)(nb * KS + step) * 4096);
        char* d = smraw + buf * 16384;
#pragma unroll
        for (int j = 0; j < 2; ++j) {
            gload_lds16(d + j * 4096 + tid * 16, sH + j * 4096 + tid * 16);
            gload_lds16(d + 8192 + j * 4096 + tid * 16, sL + j * 4096 + tid * 16);
        }
    };

    stage(0, 0);
    for (int step = 0; step < KS; ++step) {
        asm volatile("s_waitcnt vmcnt(0)" ::: "memory");
        __builtin_amdgcn_s_barrier();
        __builtin_amdgcn_sched_barrier(0);
        u32x4 ah[2][2], al2[2][2];
#pragma unroll
        for (int kc = 0; kc < 2; ++kc)
#pragma unroll
            for (int mt = 0; mt < 2; ++mt) {
                int r = r0 + mt * 16 + li;
                size_t aoff = ((size_t)(step * 8 + kc * 4 + kg) * NB + r) * 8;
                ah[kc][mt]  = *(const u32x4*)(Ah + aoff);
                al2[kc][mt] = *(const u32x4*)(Al + aoff);
            }
        if (step + 1 < KS) stage((step + 1) & 1, step + 1);
        const char* bufB = smraw + (step & 1) * 16384;
        __builtin_amdgcn_s_setprio(1);
#pragma unroll
        for (int kc = 0; kc < 2; ++kc) {
#pragma unroll
            for (int nt = 0; nt < 4; ++nt) {
                int boff = (kc * 4 + kg) * 1024 + (nt * 16 + li) * 16;
                u32x4 bh = *(const u32x4*)(bufB + boff);
                u32x4 bl = *(const u32x4*)(bufB + 8192 + boff);
#pragma unroll
                for (int mt = 0; mt < 2; ++mt) {
                    acc[mt][nt] = mfma16(ah[kc][mt], bh, acc[mt][nt]);
                    acc[mt][nt] = mfma16(ah[kc][mt], bl, acc[mt][nt]);
                    acc[mt][nt] = mfma16(al2[kc][mt], bh, acc[mt][nt]);
                }
            }
        }
        __builtin_amdgcn_s_setprio(0);
    }
    __syncthreads();

    unsigned* Sb = (unsigned*)smraw;  // [128][64]
#pragma unroll
    for (int nt = 0; nt < 4; ++nt) {
        int o = n0 + nt * 16 + li;
        float bo = (o < HID) ? bias[o] : 0.f;
#pragma unroll
        for (int mt = 0; mt < 2; ++mt)
#pragma unroll
            for (int r = 0; r < 4; ++r) {
                float c = acc[mt][nt][r] + bo;
                float v = 0.f;
                unsigned sb = 0u;
#pragma unroll
                for (int t = 0; t < TT; ++t) {
                    float h = 0.5f * (v + c);
                    if (h >= 1.0f) { sb |= (1u << t); v = 0.f; }
                    else           { v = h; }
                }
                Sb[(wave * 32 + mt * 16 + kg * 4 + r) * 64 + nt * 16 + li] = sb;
            }
    }
    __syncthreads();

    for (int rr = 0; rr < 32; ++rr) {
        int row = wave * 32 + rr;
        unsigned wv = Sb[row * 64 + l];
        unsigned myw = 0;
#pragma unroll
        for (int t = 0; t < TT; ++t) {
            unsigned long long m = __ballot((wv >> t) & 1u);
            if ((l & 31) == t) myw = (l < 32) ? (unsigned)m : (unsigned)(m >> 32);
        }
        int b = mb * 128 + row;
        obitsT[((size_t)b * KW + nb * 2 + (l >= 32)) * TT + (l & 31)] = myw;
    }
}

// ---------------------------------------------------------------------------
// i8 MFMA bit-GEMM over transposed spike bits (layout [b][kw][t]).
// Block: 4 waves (256 thr); wave owns ONE batch (32 t) x 64 cols -> acc 64
// regs (occupancy lever). Quad-buffered 8KB stages.
// ORDER-ROBUST pipeline: prologue stage(0)+vmcnt(0)+barrier guarantees buf 0
// regardless of compiler VMEM issue order; in-loop vmcnt(4) retires stage(s)
// because its 2 ops are strictly older (barrier-separated body) than the <=4
// newer ops {stage(s+1) x2, loadA(s) x2}. aw/awn+copy idiom (proven R5/R7)
// is correct under both compiler renaming choices (derivation in journal).
// EPI 0: LIF -> ballot transpose; EPI 1: mean/log_std; EPI 2: tanh head.
// ---------------------------------------------------------------------------
template<int EPI>
__global__ __launch_bounds__(256)
void bitgemm(const unsigned* __restrict__ bitsT,
             const char* __restrict__ Wh,
             const char* __restrict__ Wl,
             const float* __restrict__ bias,
             const float* __restrict__ bias2,
             unsigned* __restrict__ obitsT,
             float* __restrict__ o0,
             float* __restrict__ o1) {
    __shared__ __align__(16) char smraw[32768];  // 4x8KB bufs | epi [128][34] f32
    const int tid = threadIdx.x;
    const int w = tid >> 6, l = tid & 63;
    const int kg = l >> 4, li = l & 15;
    const int nb = blockIdx.x, n0 = nb * 64;
    const int by = blockIdx.y;
    const int b = by * 4 + w;
    const unsigned fld = (kg & 1) * 16;

    i32x4 acc[2][4][2] = {};

    auto stage = [&](int s) {
        char* d = smraw + (s & 3) * 8192;
        const char* sH = Wh + (size_t)(nb * NSTEP + s) * 4096;
        const char* sL = Wl + (size_t)(nb * NSTEP + s) * 4096;
        gload_lds16(d + tid * 16, sH + tid * 16);
        gload_lds16(d + 4096 + tid * 16, sL + tid * 16);
    };
    auto loadA = [&](int s, unsigned (&aw)[2]) {
#pragma unroll
        for (int mt = 0; mt < 2; ++mt)
            aw[mt] = bitsT[((size_t)b * KW + s * 2 + (kg >> 1)) * TT + mt * 16 + li];
    };
    auto compute = [&](int s, const unsigned (&aw)[2]) {
        const char* bufB = smraw + (s & 3) * 8192;
        u32x4 afrag[2];
#pragma unroll
        for (int mt = 0; mt < 2; ++mt) {
            unsigned wv = aw[mt] >> fld;
            u32x4 a;
#pragma unroll
            for (int j = 0; j < 4; ++j)
                a[j] = __umul24((wv >> (4 * j)) & 0xFu, 0x00204081u) & 0x01010101u;
            afrag[mt] = a;
        }
        __builtin_amdgcn_s_setprio(1);
#pragma unroll
        for (int nt = 0; nt < 4; ++nt) {
            int boff = kg * 1024 + (nt * 16 + li) * 16;
            u32x4 bh = *(const u32x4*)(bufB + boff);
            u32x4 bl = *(const u32x4*)(bufB + 4096 + boff);
#pragma unroll
            for (int mt = 0; mt < 2; ++mt) {
                acc[mt][nt][0] = mfma_i8(afrag[mt], bh, acc[mt][nt][0]);
                acc[mt][nt][1] = mfma_i8(afrag[mt], bl, acc[mt][nt][1]);
            }
        }
        __builtin_amdgcn_s_setprio(0);
    };

    unsigned aw[2], awn[2];
    // order-robust prologue: buffer 0 is provably staged before the loop
    stage(0);
    asm volatile("s_waitcnt vmcnt(0)" ::: "memory");
    __builtin_amdgcn_s_barrier();
    stage(1);
    loadA(0, aw);

    for (int s = 0; s < NSTEP; ++s) {
        asm volatile("s_waitcnt vmcnt(4)" ::: "memory");
        __builtin_amdgcn_s_barrier();
        __builtin_amdgcn_sched_barrier(0);
        if (s + 2 < NSTEP) stage(s + 2);
        if (s + 1 < NSTEP) loadA(s + 1, awn);
        compute(s, aw);
        aw[0] = awn[0];
        aw[1] = awn[1];
    }
    __syncthreads();

    // epilogue: combine limbs, 2 passes of 32 cols; wave-private 32-row slab
    float* Sf = (float*)smraw;  // [128][34]
#pragma unroll
    for (int p = 0; p < 2; ++p) {
#pragma unroll
        for (int mt = 0; mt < 2; ++mt)
#pragma unroll
            for (int ntl = 0; ntl < 2; ++ntl) {
                int nt = p * 2 + ntl;
#pragma unroll
                for (int r = 0; r < 4; ++r) {
                    int cmb = (acc[mt][nt][0][r] << 8) + acc[mt][nt][1][r];
                    Sf[(w * 32 + mt * 16 + kg * 4 + r) * 34 + ntl * 16 + li]
                        = (float)cmb * (1.f / 524288.f);
                }
            }
        __syncthreads();

        if (l < 32) {
            int c = l;
            int o = n0 + p * 32 + c;
            if (EPI == 0) {
                float bo = (o < HID) ? bias[o] : 0.f;
                float v = 0.f;
                unsigned sb = 0u;
#pragma unroll
                for (int t = 0; t < TT; ++t) {
                    float h = 0.5f * (v + Sf[(w * 32 + t) * 34 + c] + bo);
                    if (h >= 1.0f) { sb |= (1u << t); v = 0.f; }
                    else           { v = h; }
                }
                if (o >= HID) sb = 0u;
                // ballot transpose within the 32 active lanes (one b per wave)
                unsigned myw = 0;
#pragma unroll
                for (int t = 0; t < TT; ++t) {
                    unsigned long long m = __ballot((sb >> t) & 1u);
                    if (l == t) myw = (unsigned)m;
                }
                obitsT[((size_t)b * KW + nb * 2 + p) * TT + l] = myw;
            } else {
                float mx = -1e30f;
#pragma unroll
                for (int t = 0; t < TT; ++t)
                    mx = fmaxf(mx, Sf[(w * 32 + t) * 34 + c]);
                if (EPI == 1) {
                    float bo = (o < LDIM) ? bias[o] : bias2[o - LDIM];
                    float val = 0.5f * (mx + bo);
                    if (o < LDIM) o0[(size_t)b * LDIM + o] = val;
                    else          o1[(size_t)b * LDIM + (o - LDIM)] = val;
                } else {
                    o0[(size_t)b * ADIM + o] = tanhf(0.5f * (mx + bias[o]));
                }
            }
        }
        __syncthreads();
    }
}

// ---------------------------------------------------------------------------
extern "C" void kernel_launch(void* const* d_in, const int* in_sizes, int n_in,
                              void* d_out, int out_size, void* d_ws, size_t ws_size,
                              hipStream_t stream) {
    const float* state  = (const float*)d_in[0];
    const float* action = (const float*)d_in[1];
    const float* eps    = (const float*)d_in[2];
    const float* W1  = (const float*)d_in[3];
    const float* b1  = (const float*)d_in[4];
    const float* W2  = (const float*)d_in[5];
    const float* b2  = (const float*)d_in[6];
    const float* Wm  = (const float*)d_in[7];
    const float* bm  = (const float*)d_in[8];
    const float* Wls = (const float*)d_in[9];
    const float* bls = (const float*)d_in[10];
    const float* Wd1 = (const float*)d_in[11];
    const float* bd1 = (const float*)d_in[12];
    const float* Wd2 = (const float*)d_in[13];
    const float* bd2 = (const float*)d_in[14];
    const float* Wd3 = (const float*)d_in[15];
    const float* bd3 = (const float*)d_in[16];
    float* out = (float*)d_out;

    char* ws = (char*)d_ws;
    size_t off = 0;
    auto alloc = [&](size_t bytes) {
        void* p = ws + off;
        off += (bytes + 255) & ~(size_t)255;
        return p;
    };
    unsigned*       bitsT_a = (unsigned*)alloc((size_t)NB * TT * KW * 4);
    unsigned*       bitsT_b = (unsigned*)alloc((size_t)NB * TT * KW * 4);
    float*          mean_ws = (float*)   alloc((size_t)NB * LDIM * 4);
    float*          ls_ws   = (float*)   alloc((size_t)NB * LDIM * 4);
    unsigned short* Xh      = (unsigned short*)alloc((size_t)NB * DIN * 2);
    unsigned short* Xl      = (unsigned short*)alloc((size_t)NB * DIN * 2);
    char*           W2h     = (char*)alloc((size_t)KP * KP);
    char*           W2l     = (char*)alloc((size_t)KP * KP);
    char*           Wd2h    = (char*)alloc((size_t)KP * KP);
    char*           Wd2l    = (char*)alloc((size_t)KP * KP);
    char*           WmlsH   = (char*)alloc((size_t)256 * KP);
    char*           WmlsL   = (char*)alloc((size_t)256 * KP);
    char*           Wu3h    = (char*)alloc((size_t)64 * KP);
    char*           Wu3l    = (char*)alloc((size_t)64 * KP);
    unsigned short* W1h     = (unsigned short*)alloc((size_t)KP * EIN * 2);
    unsigned short* W1l     = (unsigned short*)alloc((size_t)KP * EIN * 2);
    unsigned short* Wd1h    = (unsigned short*)alloc((size_t)KP * DIN * 2);
    unsigned short* Wd1l    = (unsigned short*)alloc((size_t)KP * DIN * 2);

    dim3 blk(256);

    // weight prep (2 launches)
    wsplit_i8_all<<<(I8_E5 + 255) / 256, blk, 0, stream>>>(
        W2, Wd2, Wm, Wls, Wd3, W2h, W2l, Wd2h, Wd2l, WmlsH, WmlsL, Wu3h, Wu3l);
    wsplit_bf_all<<<(BF_E2 + 255) / 256, blk, 0, stream>>>(
        W1, Wd1, W1h, W1l, Wd1h, Wd1l);

    // encoder
    concat_xsplit_enc<<<(NB * (EIN / 8) + 255) / 256, blk, 0, stream>>>(state, action, Xh, Xl);
    lif1<5><<<dim3(12, 16), blk, 0, stream>>>(Xh, Xl, W1h, W1l, b1, bitsT_a);
    bitgemm<0><<<dim3(12, NB / 4), blk, 0, stream>>>(bitsT_a, W2h, W2l, b2, nullptr,
                                                     bitsT_b, nullptr, nullptr);
    bitgemm<1><<<dim3(4, NB / 4), blk, 0, stream>>>(bitsT_b, WmlsH, WmlsL, bm, bls,
                                                    nullptr, mean_ws, ls_ws);
    latent_xsplit<<<(NB * (DIN / 8) + 255) / 256, blk, 0, stream>>>(
        mean_ws, ls_ws, eps, state, out, Xh, Xl);

    // decoder
    lif1<6><<<dim3(12, 16), blk, 0, stream>>>(Xh, Xl, Wd1h, Wd1l, bd1, bitsT_a);
    bitgemm<0><<<dim3(12, NB / 4), blk, 0, stream>>>(bitsT_a, Wd2h, Wd2l, bd2, nullptr,
                                                     bitsT_b, nullptr, nullptr);
    bitgemm<2><<<dim3(1, NB / 4), blk, 0, stream>>>(bitsT_b, Wu3h, Wu3l, bd3, nullptr,
                                                    nullptr, out, nullptr);
}

// Round 10
// 224.845 us; speedup vs baseline: 1.1968x; 1.1968x over previous
//
#include <hip/hip_runtime.h>
#include <math.h>

#define TT   32
#define NB   2048
#define SDIM 256
#define ADIM 64
#define LDIM 128
#define HID  750
#define KP   768    // padded neuron count (k-dim of layer-2 GEMMs)
#define KW   24     // KP/32 words per batch row (bit layout [b][kw][t])
#define EIN  320    // SDIM + ADIM
#define DIN  384    // SDIM + LDIM
#define NSTEP 12    // KP / 64

typedef float    f32x4 __attribute__((ext_vector_type(4)));
typedef int      i32x4 __attribute__((ext_vector_type(4)));
typedef unsigned u32x4 __attribute__((ext_vector_type(4)));

// v_mfma_f32_16x16x32_bf16: A row=lane&15, k=(lane>>4)*8+e; B col=lane&15;
// C/D col=lane&15, row=(lane>>4)*4+reg.  (verified R2..R9)
__device__ __forceinline__ f32x4 mfma16(u32x4 a, u32x4 b, f32x4 c) {
    asm("v_mfma_f32_16x16x32_bf16 %0, %1, %2, %0" : "+v"(c) : "v"(a), "v"(b));
    return c;
}
// v_mfma_i32_16x16x64_i8: A row=lane&15, k=(lane>>4)*16 + reg*4 + byte. (verified R4..R9)
__device__ __forceinline__ i32x4 mfma_i8(u32x4 a, u32x4 b, i32x4 c) {
    asm("v_mfma_i32_16x16x64_i8 %0, %1, %2, %0" : "+v"(c) : "v"(a), "v"(b));
    return c;
}

__device__ __forceinline__ void gload_lds16(void* lds, const void* g) {
    __builtin_amdgcn_global_load_lds(
        (const __attribute__((address_space(1))) unsigned int*)g,
        (__attribute__((address_space(3))) unsigned int*)lds, 16, 0, 0);
}

// round-to-nearest-even bf16 hi/lo split (verified R2..R9)
__device__ __forceinline__ void bfsplit(float v, unsigned& hb, unsigned& lb) {
    unsigned u = __float_as_uint(v);
    hb = (u + 0x7FFFu + ((u >> 16) & 1u)) >> 16;
    float res = v - __uint_as_float(hb << 16);
    unsigned u2 = __float_as_uint(res);
    lb = (u2 + 0x7FFFu + ((u2 >> 16) & 1u)) >> 16;
}

// ---------------------------------------------------------------------------
// Merged weight-quant kernel: all five i8 2-limb splits in one launch.
// Layout per (o_blk,k_blk) 4KB block: off = kg*1024 + (o&63)*16 + (k&15).
// ---------------------------------------------------------------------------
#define I8_E1 589824          // W2   (768 rows)
#define I8_E2 1179648         // Wd2  (768 rows)
#define I8_E3 1277952         // Wm   (128 rows)
#define I8_E4 1376256         // Wls  (128 rows)
#define I8_E5 1425408         // Wd3  (64 rows)
__global__ void wsplit_i8_all(const float* __restrict__ W2,
                              const float* __restrict__ Wd2,
                              const float* __restrict__ Wm,
                              const float* __restrict__ Wls,
                              const float* __restrict__ Wd3,
                              char* __restrict__ W2h,  char* __restrict__ W2l,
                              char* __restrict__ Wd2h, char* __restrict__ Wd2l,
                              char* __restrict__ WmlsH, char* __restrict__ WmlsL,
                              char* __restrict__ Wu3h, char* __restrict__ Wu3l) {
    int i = blockIdx.x * blockDim.x + threadIdx.x;
    if (i >= I8_E5) return;
    const float* src; char* dh; char* dl; int rvalid, o_base;
    if (i < I8_E1)      { src = W2;  dh = W2h;  dl = W2l;  rvalid = HID;  o_base = 0; }
    else if (i < I8_E2) { i -= I8_E1; src = Wd2; dh = Wd2h; dl = Wd2l; rvalid = HID;  o_base = 0; }
    else if (i < I8_E3) { i -= I8_E2; src = Wm;  dh = WmlsH; dl = WmlsL; rvalid = LDIM; o_base = 0; }
    else if (i < I8_E4) { i -= I8_E3; src = Wls; dh = WmlsH; dl = WmlsL; rvalid = LDIM; o_base = 128; }
    else                { i -= I8_E4; src = Wd3; dh = Wu3h; dl = Wu3l; rvalid = ADIM; o_base = 0; }
    int r = i / KP, k = i % KP;
    float v = (r < rvalid && k < HID) ? src[r * HID + k] : 0.f;
    int q = (int)rintf(v * 524288.f);
    int lo = (q << 24) >> 24;           // sext low byte
    int hi = (q - lo) >> 8;
    int o = o_base + r;
    size_t di = (size_t)((o >> 6) * NSTEP + (k >> 6)) * 4096
              + ((k >> 4) & 3) * 1024 + (o & 63) * 16 + (k & 15);
    dh[di] = (char)hi;
    dl[di] = (char)lo;
}

// ---------------------------------------------------------------------------
// Merged layer-1 weight split (W1 KS=5, Wd1 KS=6), bf16 hi/lo packed per
// (nb,ks64) 8KB block: elem = (kc*4+kg)*512 + (o&63)*8 + (k&7).
// ---------------------------------------------------------------------------
#define BF_E1 245760          // W1 (KP x EIN)
#define BF_E2 540672          // Wd1 (KP x DIN)
__global__ void wsplit_bf_all(const float* __restrict__ W1,
                              const float* __restrict__ Wd1,
                              unsigned short* __restrict__ W1h,
                              unsigned short* __restrict__ W1l,
                              unsigned short* __restrict__ Wd1h,
                              unsigned short* __restrict__ Wd1l) {
    int i = blockIdx.x * blockDim.x + threadIdx.x;
    if (i >= BF_E2) return;
    const float* src; unsigned short* dh; unsigned short* dl; int K, KS;
    if (i < BF_E1) { src = W1; dh = W1h; dl = W1l; K = EIN; KS = 5; }
    else { i -= BF_E1; src = Wd1; dh = Wd1h; dl = Wd1l; K = DIN; KS = 6; }
    int r = i / K, k = i % K;
    float v = (r < HID) ? src[r * K + k] : 0.f;
    unsigned hb, lb;
    bfsplit(v, hb, lb);
    size_t di = ((size_t)((r >> 6) * KS + (k >> 6)) * 8
               + ((k >> 5) & 1) * 4 + ((k >> 3) & 3)) * 512 + (r & 63) * 8 + (k & 7);
    dh[di] = (unsigned short)hb;
    dl[di] = (unsigned short)lb;
}

// ---------------------------------------------------------------------------
// Fused encoder concat + bf16 hi/lo split, A layout idx = ((k>>3)*NB + b)*8 + (k&7)
// ---------------------------------------------------------------------------
__global__ void concat_xsplit_enc(const float* __restrict__ state,
                                  const float* __restrict__ action,
                                  unsigned short* __restrict__ Xh,
                                  unsigned short* __restrict__ Xl) {
    int t = blockIdx.x * blockDim.x + threadIdx.x;
    if (t >= NB * (EIN / 8)) return;
    int b = t & (NB - 1), c8 = t >> 11;
    float vals[8];
    if (c8 < SDIM / 8) {
        const float* src = state + (size_t)b * SDIM + c8 * 8;
#pragma unroll
        for (int j = 0; j < 8; ++j) vals[j] = src[j];
    } else {
        const float* src = action + (size_t)b * ADIM + (c8 * 8 - SDIM);
#pragma unroll
        for (int j = 0; j < 8; ++j) vals[j] = src[j];
    }
    unsigned hs[8], ls[8];
#pragma unroll
    for (int j = 0; j < 8; ++j) bfsplit(vals[j], hs[j], ls[j]);
    u32x4 ph, pl;
#pragma unroll
    for (int j = 0; j < 4; ++j) {
        ph[j] = hs[2 * j] | (hs[2 * j + 1] << 16);
        pl[j] = ls[2 * j] | (ls[2 * j + 1] << 16);
    }
    *(u32x4*)(Xh + (size_t)t * 8) = ph;
    *(u32x4*)(Xl + (size_t)t * 8) = pl;
}

// ---------------------------------------------------------------------------
// Fused latent + decoder concat + split.
// ---------------------------------------------------------------------------
__global__ void latent_xsplit(const float* __restrict__ mean_ws,
                              const float* __restrict__ ls_ws,
                              const float* __restrict__ eps,
                              const float* __restrict__ state,
                              float* __restrict__ out,
                              unsigned short* __restrict__ Xh,
                              unsigned short* __restrict__ Xl) {
    int t = blockIdx.x * blockDim.x + threadIdx.x;
    if (t >= NB * (DIN / 8)) return;
    int b = t & (NB - 1), c8 = t >> 11;
    float vals[8];
    if (c8 < SDIM / 8) {
        const float* src = state + (size_t)b * SDIM + c8 * 8;
#pragma unroll
        for (int j = 0; j < 8; ++j) vals[j] = src[j];
    } else {
        int o0 = c8 * 8 - SDIM;
#pragma unroll
        for (int j = 0; j < 8; ++j) {
            int o = o0 + j;
            float m = mean_ws[(size_t)b * LDIM + o];
            float l = ls_ws[(size_t)b * LDIM + o];
            l = fminf(fmaxf(l, -4.0f), 15.0f);
            float s = expf(l);
            vals[j] = m + s * eps[(size_t)b * LDIM + o];
            out[NB * ADIM + (size_t)b * LDIM + o] = m;
            out[NB * ADIM + NB * LDIM + (size_t)b * LDIM + o] = s;
        }
    }
    unsigned hs[8], ls[8];
#pragma unroll
    for (int j = 0; j < 8; ++j) bfsplit(vals[j], hs[j], ls[j]);
    u32x4 ph, pl;
#pragma unroll
    for (int j = 0; j < 4; ++j) {
        ph[j] = hs[2 * j] | (hs[2 * j + 1] << 16);
        pl[j] = ls[2 * j] | (ls[2 * j + 1] << 16);
    }
    *(u32x4*)(Xh + (size_t)t * 8) = ph;
    *(u32x4*)(Xl + (size_t)t * 8) = pl;
}

// ---------------------------------------------------------------------------
// Layer-1: bf16 3-product MFMA GEMM + const-input LIF + ballot bit-transpose.
// Block: 4 waves, M=64 rows (wave: 16), N=64, grid (12,32) — doubled blocks
// halve the per-thread epilogue scans (16 elems) and cover more CUs.
// Main loop: R7-proven per-step vmcnt(0)-drain structure (order-robust).
// ---------------------------------------------------------------------------
template<int KS>
__global__ __launch_bounds__(256)
void lif1(const unsigned short* __restrict__ Ah,
          const unsigned short* __restrict__ Al,
          const unsigned short* __restrict__ Wh,
          const unsigned short* __restrict__ Wl,
          const float* __restrict__ bias,
          unsigned* __restrict__ obitsT) {
    __shared__ __align__(16) char smraw[32768];  // 2x16KB bufs | epi Sb[64][64] u32
    const int tid = threadIdx.x, w = tid >> 6, l = tid & 63;
    const int kg = l >> 4, li = l & 15;
    const int nb = blockIdx.x, n0 = nb * 64, mb = blockIdx.y;
    const int r0 = mb * 64 + w * 16;
    f32x4 acc[4] = {};

    auto stage = [&](int buf, int step) {
        const char* sH = (const char*)(Wh + (size_t)(nb * KS + step) * 4096);
        const char* sL = (const char*)(Wl + (size_t)(nb * KS + step) * 4096);
        char* d = smraw + buf * 16384;
#pragma unroll
        for (int j = 0; j < 2; ++j) {
            gload_lds16(d + j * 4096 + tid * 16, sH + j * 4096 + tid * 16);
            gload_lds16(d + 8192 + j * 4096 + tid * 16, sL + j * 4096 + tid * 16);
        }
    };

    stage(0, 0);
    for (int step = 0; step < KS; ++step) {
        asm volatile("s_waitcnt vmcnt(0)" ::: "memory");
        __builtin_amdgcn_s_barrier();
        __builtin_amdgcn_sched_barrier(0);
        u32x4 ah[2], al2[2];
#pragma unroll
        for (int kc = 0; kc < 2; ++kc) {
            size_t aoff = ((size_t)(step * 8 + kc * 4 + kg) * NB + r0 + li) * 8;
            ah[kc]  = *(const u32x4*)(Ah + aoff);
            al2[kc] = *(const u32x4*)(Al + aoff);
        }
        if (step + 1 < KS) stage((step + 1) & 1, step + 1);
        const char* bufB = smraw + (step & 1) * 16384;
        __builtin_amdgcn_s_setprio(1);
#pragma unroll
        for (int kc = 0; kc < 2; ++kc) {
#pragma unroll
            for (int nt = 0; nt < 4; ++nt) {
                int boff = (kc * 4 + kg) * 1024 + (nt * 16 + li) * 16;
                u32x4 bh = *(const u32x4*)(bufB + boff);
                u32x4 bl = *(const u32x4*)(bufB + 8192 + boff);
                acc[nt] = mfma16(ah[kc], bh, acc[nt]);
                acc[nt] = mfma16(ah[kc], bl, acc[nt]);
                acc[nt] = mfma16(al2[kc], bh, acc[nt]);
            }
        }
        __builtin_amdgcn_s_setprio(0);
    }
    __syncthreads();   // slab aliases staging buffers

    // const-input LIF scan (16 elems/thread) -> wave-private slab rows
    unsigned* Sb = (unsigned*)smraw;  // [64][64]
#pragma unroll
    for (int nt = 0; nt < 4; ++nt) {
        int o = n0 + nt * 16 + li;
        float bo = (o < HID) ? bias[o] : 0.f;
#pragma unroll
        for (int r = 0; r < 4; ++r) {
            float c = acc[nt][r] + bo;
            float v = 0.f;
            unsigned sb = 0u;
#pragma unroll
            for (int t = 0; t < TT; ++t) {
                float h = 0.5f * (v + c);
                if (h >= 1.0f) { sb |= (1u << t); v = 0.f; }
                else           { v = h; }
            }
            Sb[(w * 16 + kg * 4 + r) * 64 + nt * 16 + li] = sb;
        }
    }
    // wave-private rows: no barrier needed (in-wave DS ordering)

    // ballot transpose: rows [w*16, w*16+16) -> bitsT[b][kw][t]
    for (int rr = 0; rr < 16; ++rr) {
        int row = w * 16 + rr;
        unsigned wv = Sb[row * 64 + l];
        unsigned myw = 0;
#pragma unroll
        for (int t = 0; t < TT; ++t) {
            unsigned long long m = __ballot((wv >> t) & 1u);
            if ((l & 31) == t) myw = (l < 32) ? (unsigned)m : (unsigned)(m >> 32);
        }
        int b = mb * 64 + row;
        obitsT[((size_t)b * KW + nb * 2 + (l >= 32)) * TT + (l & 31)] = myw;
    }
}

// ---------------------------------------------------------------------------
// i8 MFMA bit-GEMM over transposed spike bits (layout [b][kw][t]).
// Block: 4 waves (256 thr); wave owns ONE batch (32 t) x 64 cols.
// Main loop: R9-proven order-robust pipeline (quad-buffer, prologue
// stage(0)+vmcnt(0)+barrier, in-loop vmcnt(4)).
// Epilogue: single pass, ALL 64 lanes — one output column per lane over a
// wave-private [32][66] f32 slab; full-wave ballot transpose.
// EPI 0: LIF -> bitsT; EPI 1: mean/log_std heads; EPI 2: tanh action head.
// ---------------------------------------------------------------------------
template<int EPI>
__global__ __launch_bounds__(256)
void bitgemm(const unsigned* __restrict__ bitsT,
             const char* __restrict__ Wh,
             const char* __restrict__ Wl,
             const float* __restrict__ bias,
             const float* __restrict__ bias2,
             unsigned* __restrict__ obitsT,
             float* __restrict__ o0,
             float* __restrict__ o1) {
    __shared__ __align__(16) char smraw[34816];  // 4x8KB bufs | epi [4][32][66] f32
    const int tid = threadIdx.x;
    const int w = tid >> 6, l = tid & 63;
    const int kg = l >> 4, li = l & 15;
    const int nb = blockIdx.x, n0 = nb * 64;
    const int by = blockIdx.y;
    const int b = by * 4 + w;
    const unsigned fld = (kg & 1) * 16;

    i32x4 acc[2][4][2] = {};

    auto stage = [&](int s) {
        char* d = smraw + (s & 3) * 8192;
        const char* sH = Wh + (size_t)(nb * NSTEP + s) * 4096;
        const char* sL = Wl + (size_t)(nb * NSTEP + s) * 4096;
        gload_lds16(d + tid * 16, sH + tid * 16);
        gload_lds16(d + 4096 + tid * 16, sL + tid * 16);
    };
    auto loadA = [&](int s, unsigned (&aw)[2]) {
#pragma unroll
        for (int mt = 0; mt < 2; ++mt)
            aw[mt] = bitsT[((size_t)b * KW + s * 2 + (kg >> 1)) * TT + mt * 16 + li];
    };
    auto compute = [&](int s, const unsigned (&aw)[2]) {
        const char* bufB = smraw + (s & 3) * 8192;
        u32x4 afrag[2];
#pragma unroll
        for (int mt = 0; mt < 2; ++mt) {
            unsigned wv = aw[mt] >> fld;
            u32x4 a;
#pragma unroll
            for (int j = 0; j < 4; ++j)
                a[j] = __umul24((wv >> (4 * j)) & 0xFu, 0x00204081u) & 0x01010101u;
            afrag[mt] = a;
        }
        __builtin_amdgcn_s_setprio(1);
#pragma unroll
        for (int nt = 0; nt < 4; ++nt) {
            int boff = kg * 1024 + (nt * 16 + li) * 16;
            u32x4 bh = *(const u32x4*)(bufB + boff);
            u32x4 bl = *(const u32x4*)(bufB + 4096 + boff);
#pragma unroll
            for (int mt = 0; mt < 2; ++mt) {
                acc[mt][nt][0] = mfma_i8(afrag[mt], bh, acc[mt][nt][0]);
                acc[mt][nt][1] = mfma_i8(afrag[mt], bl, acc[mt][nt][1]);
            }
        }
        __builtin_amdgcn_s_setprio(0);
    };

    unsigned aw[2], awn[2];
    // order-robust prologue: buffer 0 is provably staged before the loop
    stage(0);
    asm volatile("s_waitcnt vmcnt(0)" ::: "memory");
    __builtin_amdgcn_s_barrier();
    stage(1);
    loadA(0, aw);

    for (int s = 0; s < NSTEP; ++s) {
        asm volatile("s_waitcnt vmcnt(4)" ::: "memory");
        __builtin_amdgcn_s_barrier();
        __builtin_amdgcn_sched_barrier(0);
        if (s + 2 < NSTEP) stage(s + 2);
        if (s + 1 < NSTEP) loadA(s + 1, awn);
        compute(s, aw);
        aw[0] = awn[0];
        aw[1] = awn[1];
    }
    __syncthreads();   // slab aliases staging buffers

    // store C tile to wave-private slab [32][66]: row t = mt*16+kg*4+r, col nt*16+li
    float* Sf = (float*)smraw + (size_t)w * 32 * 66;
#pragma unroll
    for (int mt = 0; mt < 2; ++mt)
#pragma unroll
        for (int nt = 0; nt < 4; ++nt)
#pragma unroll
            for (int r = 0; r < 4; ++r) {
                int cmb = (acc[mt][nt][0][r] << 8) + acc[mt][nt][1][r];
                Sf[(mt * 16 + kg * 4 + r) * 66 + nt * 16 + li]
                    = (float)cmb * (1.f / 524288.f);
            }
    // wave-private: no barrier (in-wave DS ordering)

    // single pass: one column per lane (all 64 lanes active)
    int o = n0 + l;
    if (EPI == 0) {
        float bo = (o < HID) ? bias[o] : 0.f;
        float v = 0.f;
        unsigned sb = 0u;
#pragma unroll
        for (int t = 0; t < TT; ++t) {
            float h = 0.5f * (v + Sf[t * 66 + l] + bo);
            if (h >= 1.0f) { sb |= (1u << t); v = 0.f; }
            else           { v = h; }
        }
        if (o >= HID) sb = 0u;
        // full-wave ballot transpose: low 32 lanes -> kw even, high -> kw odd
        unsigned myw = 0;
#pragma unroll
        for (int t = 0; t < TT; ++t) {
            unsigned long long m = __ballot((sb >> t) & 1u);
            if ((l & 31) == t) myw = (l < 32) ? (unsigned)m : (unsigned)(m >> 32);
        }
        obitsT[((size_t)b * KW + nb * 2 + (l >= 32)) * TT + (l & 31)] = myw;
    } else {
        float mx = -1e30f;
#pragma unroll
        for (int t = 0; t < TT; ++t)
            mx = fmaxf(mx, Sf[t * 66 + l]);
        if (EPI == 1) {
            float bo = (o < LDIM) ? bias[o] : bias2[o - LDIM];
            float val = 0.5f * (mx + bo);
            if (o < LDIM) o0[(size_t)b * LDIM + o] = val;
            else          o1[(size_t)b * LDIM + (o - LDIM)] = val;
        } else {
            o0[(size_t)b * ADIM + l] = tanhf(0.5f * (mx + bias[l]));
        }
    }
}

// ---------------------------------------------------------------------------
extern "C" void kernel_launch(void* const* d_in, const int* in_sizes, int n_in,
                              void* d_out, int out_size, void* d_ws, size_t ws_size,
                              hipStream_t stream) {
    const float* state  = (const float*)d_in[0];
    const float* action = (const float*)d_in[1];
    const float* eps    = (const float*)d_in[2];
    const float* W1  = (const float*)d_in[3];
    const float* b1  = (const float*)d_in[4];
    const float* W2  = (const float*)d_in[5];
    const float* b2  = (const float*)d_in[6];
    const float* Wm  = (const float*)d_in[7];
    const float* bm  = (const float*)d_in[8];
    const float* Wls = (const float*)d_in[9];
    const float* bls = (const float*)d_in[10];
    const float* Wd1 = (const float*)d_in[11];
    const float* bd1 = (const float*)d_in[12];
    const float* Wd2 = (const float*)d_in[13];
    const float* bd2 = (const float*)d_in[14];
    const float* Wd3 = (const float*)d_in[15];
    const float* bd3 = (const float*)d_in[16];
    float* out = (float*)d_out;

    char* ws = (char*)d_ws;
    size_t off = 0;
    auto alloc = [&](size_t bytes) {
        void* p = ws + off;
        off += (bytes + 255) & ~(size_t)255;
        return p;
    };
    unsigned*       bitsT_a = (unsigned*)alloc((size_t)NB * TT * KW * 4);
    unsigned*       bitsT_b = (unsigned*)alloc((size_t)NB * TT * KW * 4);
    float*          mean_ws = (float*)   alloc((size_t)NB * LDIM * 4);
    float*          ls_ws   = (float*)   alloc((size_t)NB * LDIM * 4);
    unsigned short* Xh      = (unsigned short*)alloc((size_t)NB * DIN * 2);
    unsigned short* Xl      = (unsigned short*)alloc((size_t)NB * DIN * 2);
    char*           W2h     = (char*)alloc((size_t)KP * KP);
    char*           W2l     = (char*)alloc((size_t)KP * KP);
    char*           Wd2h    = (char*)alloc((size_t)KP * KP);
    char*           Wd2l    = (char*)alloc((size_t)KP * KP);
    char*           WmlsH   = (char*)alloc((size_t)256 * KP);
    char*           WmlsL   = (char*)alloc((size_t)256 * KP);
    char*           Wu3h    = (char*)alloc((size_t)64 * KP);
    char*           Wu3l    = (char*)alloc((size_t)64 * KP);
    unsigned short* W1h     = (unsigned short*)alloc((size_t)KP * EIN * 2);
    unsigned short* W1l     = (unsigned short*)alloc((size_t)KP * EIN * 2);
    unsigned short* Wd1h    = (unsigned short*)alloc((size_t)KP * DIN * 2);
    unsigned short* Wd1l    = (unsigned short*)alloc((size_t)KP * DIN * 2);

    dim3 blk(256);

    // weight prep (2 launches)
    wsplit_i8_all<<<(I8_E5 + 255) / 256, blk, 0, stream>>>(
        W2, Wd2, Wm, Wls, Wd3, W2h, W2l, Wd2h, Wd2l, WmlsH, WmlsL, Wu3h, Wu3l);
    wsplit_bf_all<<<(BF_E2 + 255) / 256, blk, 0, stream>>>(
        W1, Wd1, W1h, W1l, Wd1h, Wd1l);

    // encoder
    concat_xsplit_enc<<<(NB * (EIN / 8) + 255) / 256, blk, 0, stream>>>(state, action, Xh, Xl);
    lif1<5><<<dim3(12, 32), blk, 0, stream>>>(Xh, Xl, W1h, W1l, b1, bitsT_a);
    bitgemm<0><<<dim3(12, NB / 4), blk, 0, stream>>>(bitsT_a, W2h, W2l, b2, nullptr,
                                                     bitsT_b, nullptr, nullptr);
    bitgemm<1><<<dim3(4, NB / 4), blk, 0, stream>>>(bitsT_b, WmlsH, WmlsL, bm, bls,
                                                    nullptr, mean_ws, ls_ws);
    latent_xsplit<<<(NB * (DIN / 8) + 255) / 256, blk, 0, stream>>>(
        mean_ws, ls_ws, eps, state, out, Xh, Xl);

    // decoder
    lif1<6><<<dim3(12, 32), blk, 0, stream>>>(Xh, Xl, Wd1h, Wd1l, bd1, bitsT_a);
    bitgemm<0><<<dim3(12, NB / 4), blk, 0, stream>>>(bitsT_a, Wd2h, Wd2l, bd2, nullptr,
                                                     bitsT_b, nullptr, nullptr);
    bitgemm<2><<<dim3(1, NB / 4), blk, 0, stream>>>(bitsT_b, Wu3h, Wu3l, bd3, nullptr,
                                                    nullptr, out, nullptr);
}

// Round 13
// 223.788 us; speedup vs baseline: 1.2025x; 1.0047x over previous
//
#include <hip/hip_runtime.h>
#include <math.h>

#define TT   32
#define NB   2048
#define SDIM 256
#define ADIM 64
#define LDIM 128
#define HID  750
#define KP   768    // padded neuron count (k-dim of layer-2 GEMMs)
#define KW   24     // KP/32 words per batch row (bit layout [b][kw][t])
#define EIN  320    // SDIM + ADIM
#define DIN  384    // SDIM + LDIM
#define NSTEP 12    // KP / 64

typedef float    f32x4 __attribute__((ext_vector_type(4)));
typedef int      i32x4 __attribute__((ext_vector_type(4)));
typedef unsigned u32x4 __attribute__((ext_vector_type(4)));

// v_mfma_f32_16x16x32_bf16: A row=lane&15, k=(lane>>4)*8+e; B col=lane&15;
// C/D col=lane&15, row=(lane>>4)*4+reg.  (verified R2..R10)
__device__ __forceinline__ f32x4 mfma16(u32x4 a, u32x4 b, f32x4 c) {
    asm("v_mfma_f32_16x16x32_bf16 %0, %1, %2, %0" : "+v"(c) : "v"(a), "v"(b));
    return c;
}
// v_mfma_i32_16x16x64_i8: A row=lane&15, k=(lane>>4)*16 + reg*4 + byte. (verified R4..R10)
__device__ __forceinline__ i32x4 mfma_i8(u32x4 a, u32x4 b, i32x4 c) {
    asm("v_mfma_i32_16x16x64_i8 %0, %1, %2, %0" : "+v"(c) : "v"(a), "v"(b));
    return c;
}

__device__ __forceinline__ void gload_lds16(void* lds, const void* g) {
    __builtin_amdgcn_global_load_lds(
        (const __attribute__((address_space(1))) unsigned int*)g,
        (__attribute__((address_space(3))) unsigned int*)lds, 16, 0, 0);
}

// round-to-nearest-even bf16 hi/lo split (verified R2..R10)
__device__ __forceinline__ void bfsplit(float v, unsigned& hb, unsigned& lb) {
    unsigned u = __float_as_uint(v);
    hb = (u + 0x7FFFu + ((u >> 16) & 1u)) >> 16;
    float res = v - __uint_as_float(hb << 16);
    unsigned u2 = __float_as_uint(res);
    lb = (u2 + 0x7FFFu + ((u2 >> 16) & 1u)) >> 16;
}

// ---------------------------------------------------------------------------
// Merged weight-quant kernel: all five i8 2-limb splits in one launch.
// Layout per (o_blk,k_blk) 4KB block: off = kg*1024 + (o&63)*16 + (k&15).
// ---------------------------------------------------------------------------
#define I8_E1 589824          // W2   (768 rows)
#define I8_E2 1179648         // Wd2  (768 rows)
#define I8_E3 1277952         // Wm   (128 rows)
#define I8_E4 1376256         // Wls  (128 rows)
#define I8_E5 1425408         // Wd3  (64 rows)
__global__ void wsplit_i8_all(const float* __restrict__ W2,
                              const float* __restrict__ Wd2,
                              const float* __restrict__ Wm,
                              const float* __restrict__ Wls,
                              const float* __restrict__ Wd3,
                              char* __restrict__ W2h,  char* __restrict__ W2l,
                              char* __restrict__ Wd2h, char* __restrict__ Wd2l,
                              char* __restrict__ WmlsH, char* __restrict__ WmlsL,
                              char* __restrict__ Wu3h, char* __restrict__ Wu3l) {
    int i = blockIdx.x * blockDim.x + threadIdx.x;
    if (i >= I8_E5) return;
    const float* src; char* dh; char* dl; int rvalid, o_base;
    if (i < I8_E1)      { src = W2;  dh = W2h;  dl = W2l;  rvalid = HID;  o_base = 0; }
    else if (i < I8_E2) { i -= I8_E1; src = Wd2; dh = Wd2h; dl = Wd2l; rvalid = HID;  o_base = 0; }
    else if (i < I8_E3) { i -= I8_E2; src = Wm;  dh = WmlsH; dl = WmlsL; rvalid = LDIM; o_base = 0; }
    else if (i < I8_E4) { i -= I8_E3; src = Wls; dh = WmlsH; dl = WmlsL; rvalid = LDIM; o_base = 128; }
    else                { i -= I8_E4; src = Wd3; dh = Wu3h; dl = Wu3l; rvalid = ADIM; o_base = 0; }
    int r = i / KP, k = i % KP;
    float v = (r < rvalid && k < HID) ? src[r * HID + k] : 0.f;
    int q = (int)rintf(v * 524288.f);
    int lo = (q << 24) >> 24;           // sext low byte
    int hi = (q - lo) >> 8;
    int o = o_base + r;
    size_t di = (size_t)((o >> 6) * NSTEP + (k >> 6)) * 4096
              + ((k >> 4) & 3) * 1024 + (o & 63) * 16 + (k & 15);
    dh[di] = (char)hi;
    dl[di] = (char)lo;
}

// ---------------------------------------------------------------------------
// Merged layer-1 weight split (W1 KS=5, Wd1 KS=6), bf16 hi/lo packed per
// (nb,ks64) 8KB block: elem = (kc*4+kg)*512 + (o&63)*8 + (k&7).
// ---------------------------------------------------------------------------
#define BF_E1 245760          // W1 (KP x EIN)
#define BF_E2 540672          // Wd1 (KP x DIN)
__global__ void wsplit_bf_all(const float* __restrict__ W1,
                              const float* __restrict__ Wd1,
                              unsigned short* __restrict__ W1h,
                              unsigned short* __restrict__ W1l,
                              unsigned short* __restrict__ Wd1h,
                              unsigned short* __restrict__ Wd1l) {
    int i = blockIdx.x * blockDim.x + threadIdx.x;
    if (i >= BF_E2) return;
    const float* src; unsigned short* dh; unsigned short* dl; int K, KS;
    if (i < BF_E1) { src = W1; dh = W1h; dl = W1l; K = EIN; KS = 5; }
    else { i -= BF_E1; src = Wd1; dh = Wd1h; dl = Wd1l; K = DIN; KS = 6; }
    int r = i / K, k = i % K;
    float v = (r < HID) ? src[r * K + k] : 0.f;
    unsigned hb, lb;
    bfsplit(v, hb, lb);
    size_t di = ((size_t)((r >> 6) * KS + (k >> 6)) * 8
               + ((k >> 5) & 1) * 4 + ((k >> 3) & 3)) * 512 + (r & 63) * 8 + (k & 7);
    dh[di] = (unsigned short)hb;
    dl[di] = (unsigned short)lb;
}

// ---------------------------------------------------------------------------
// Fused encoder concat + bf16 hi/lo split, A layout idx = ((k>>3)*NB + b)*8 + (k&7)
// ---------------------------------------------------------------------------
__global__ void concat_xsplit_enc(const float* __restrict__ state,
                                  const float* __restrict__ action,
                                  unsigned short* __restrict__ Xh,
                                  unsigned short* __restrict__ Xl) {
    int t = blockIdx.x * blockDim.x + threadIdx.x;
    if (t >= NB * (EIN / 8)) return;
    int b = t & (NB - 1), c8 = t >> 11;
    float vals[8];
    if (c8 < SDIM / 8) {
        const float* src = state + (size_t)b * SDIM + c8 * 8;
#pragma unroll
        for (int j = 0; j < 8; ++j) vals[j] = src[j];
    } else {
        const float* src = action + (size_t)b * ADIM + (c8 * 8 - SDIM);
#pragma unroll
        for (int j = 0; j < 8; ++j) vals[j] = src[j];
    }
    unsigned hs[8], ls[8];
#pragma unroll
    for (int j = 0; j < 8; ++j) bfsplit(vals[j], hs[j], ls[j]);
    u32x4 ph, pl;
#pragma unroll
    for (int j = 0; j < 4; ++j) {
        ph[j] = hs[2 * j] | (hs[2 * j + 1] << 16);
        pl[j] = ls[2 * j] | (ls[2 * j + 1] << 16);
    }
    *(u32x4*)(Xh + (size_t)t * 8) = ph;
    *(u32x4*)(Xl + (size_t)t * 8) = pl;
}

// ---------------------------------------------------------------------------
// Fused latent + decoder concat + split.
// ---------------------------------------------------------------------------
__global__ void latent_xsplit(const float* __restrict__ mean_ws,
                              const float* __restrict__ ls_ws,
                              const float* __restrict__ eps,
                              const float* __restrict__ state,
                              float* __restrict__ out,
                              unsigned short* __restrict__ Xh,
                              unsigned short* __restrict__ Xl) {
    int t = blockIdx.x * blockDim.x + threadIdx.x;
    if (t >= NB * (DIN / 8)) return;
    int b = t & (NB - 1), c8 = t >> 11;
    float vals[8];
    if (c8 < SDIM / 8) {
        const float* src = state + (size_t)b * SDIM + c8 * 8;
#pragma unroll
        for (int j = 0; j < 8; ++j) vals[j] = src[j];
    } else {
        int o0 = c8 * 8 - SDIM;
#pragma unroll
        for (int j = 0; j < 8; ++j) {
            int o = o0 + j;
            float m = mean_ws[(size_t)b * LDIM + o];
            float l = ls_ws[(size_t)b * LDIM + o];
            l = fminf(fmaxf(l, -4.0f), 15.0f);
            float s = expf(l);
            vals[j] = m + s * eps[(size_t)b * LDIM + o];
            out[NB * ADIM + (size_t)b * LDIM + o] = m;
            out[NB * ADIM + NB * LDIM + (size_t)b * LDIM + o] = s;
        }
    }
    unsigned hs[8], ls[8];
#pragma unroll
    for (int j = 0; j < 8; ++j) bfsplit(vals[j], hs[j], ls[j]);
    u32x4 ph, pl;
#pragma unroll
    for (int j = 0; j < 4; ++j) {
        ph[j] = hs[2 * j] | (hs[2 * j + 1] << 16);
        pl[j] = ls[2 * j] | (ls[2 * j + 1] << 16);
    }
    *(u32x4*)(Xh + (size_t)t * 8) = ph;
    *(u32x4*)(Xl + (size_t)t * 8) = pl;
}

// ---------------------------------------------------------------------------
// Layer-1 (R10-verbatim, proven): bf16 3-product MFMA GEMM + const-input LIF
// + ballot bit-transpose -> bitsT[b][kw][t]. Per-step vmcnt(0)-drain loop
// (order-robust by construction). Block: 4 waves, M=64, N=64, grid (12,32).
// ---------------------------------------------------------------------------
template<int KS>
__global__ __launch_bounds__(256)
void lif1(const unsigned short* __restrict__ Ah,
          const unsigned short* __restrict__ Al,
          const unsigned short* __restrict__ Wh,
          const unsigned short* __restrict__ Wl,
          const float* __restrict__ bias,
          unsigned* __restrict__ obitsT) {
    __shared__ __align__(16) char smraw[32768];  // 2x16KB bufs | epi Sb[64][64] u32
    const int tid = threadIdx.x, w = tid >> 6, l = tid & 63;
    const int kg = l >> 4, li = l & 15;
    const int nb = blockIdx.x, n0 = nb * 64, mb = blockIdx.y;
    const int r0 = mb * 64 + w * 16;
    f32x4 acc[4] = {};

    auto stage = [&](int buf, int step) {
        const char* sH = (const char*)(Wh + (size_t)(nb * KS + step) * 4096);
        const char* sL = (const char*)(Wl + (size_t)(nb * KS + step) * 4096);
        char* d = smraw + buf * 16384;
#pragma unroll
        for (int j = 0; j < 2; ++j) {
            gload_lds16(d + j * 4096 + tid * 16, sH + j * 4096 + tid * 16);
            gload_lds16(d + 8192 + j * 4096 + tid * 16, sL + j * 4096 + tid * 16);
        }
    };

    stage(0, 0);
    for (int step = 0; step < KS; ++step) {
        asm volatile("s_waitcnt vmcnt(0)" ::: "memory");
        __builtin_amdgcn_s_barrier();
        __builtin_amdgcn_sched_barrier(0);
        u32x4 ah[2], al2[2];
#pragma unroll
        for (int kc = 0; kc < 2; ++kc) {
            size_t aoff = ((size_t)(step * 8 + kc * 4 + kg) * NB + r0 + li) * 8;
            ah[kc]  = *(const u32x4*)(Ah + aoff);
            al2[kc] = *(const u32x4*)(Al + aoff);
        }
        if (step + 1 < KS) stage((step + 1) & 1, step + 1);
        const char* bufB = smraw + (step & 1) * 16384;
        __builtin_amdgcn_s_setprio(1);
#pragma unroll
        for (int kc = 0; kc < 2; ++kc) {
#pragma unroll
            for (int nt = 0; nt < 4; ++nt) {
                int boff = (kc * 4 + kg) * 1024 + (nt * 16 + li) * 16;
                u32x4 bh = *(const u32x4*)(bufB + boff);
                u32x4 bl = *(const u32x4*)(bufB + 8192 + boff);
                acc[nt] = mfma16(ah[kc], bh, acc[nt]);
                acc[nt] = mfma16(ah[kc], bl, acc[nt]);
                acc[nt] = mfma16(al2[kc], bh, acc[nt]);
            }
        }
        __builtin_amdgcn_s_setprio(0);
    }
    __syncthreads();   // slab aliases staging buffers

    // const-input LIF scan (16 elems/thread) -> wave-private slab rows
    unsigned* Sb = (unsigned*)smraw;  // [64][64]
#pragma unroll
    for (int nt = 0; nt < 4; ++nt) {
        int o = n0 + nt * 16 + li;
        float bo = (o < HID) ? bias[o] : 0.f;
#pragma unroll
        for (int r = 0; r < 4; ++r) {
            float c = acc[nt][r] + bo;
            float v = 0.f;
            unsigned sb = 0u;
#pragma unroll
            for (int t = 0; t < TT; ++t) {
                float h = 0.5f * (v + c);
                if (h >= 1.0f) { sb |= (1u << t); v = 0.f; }
                else           { v = h; }
            }
            Sb[(w * 16 + kg * 4 + r) * 64 + nt * 16 + li] = sb;
        }
    }
    // wave-private rows: no barrier needed (in-wave DS ordering)

    // ballot transpose: rows [w*16, w*16+16) -> bitsT[b][kw][t]
    for (int rr = 0; rr < 16; ++rr) {
        int row = w * 16 + rr;
        unsigned wv = Sb[row * 64 + l];
        unsigned myw = 0;
#pragma unroll
        for (int t = 0; t < TT; ++t) {
            unsigned long long m = __ballot((wv >> t) & 1u);
            if ((l & 31) == t) myw = (l < 32) ? (unsigned)m : (unsigned)(m >> 32);
        }
        int b = mb * 64 + row;
        obitsT[((size_t)b * KW + nb * 2 + (l >= 32)) * TT + (l & 31)] = myw;
    }
}

// ---------------------------------------------------------------------------
// i8 MFMA bit-GEMM over transposed spike bits (layout [b][kw][t]).
// R10-proven structure: 4 waves, 1 batch/wave, K-step 64, quad-buffered 8KB
// stages, pinned prologue, in-loop vmcnt(4) (guarantee re-verified under
// arbitrary issue order for s in [0, NSTEP-1)), plus the ONE hardening vs
// R10: the final K-step is PEELED with a full vmcnt(0) drain — at the tail
// the pipeline is empty, so no counted wait can prove stage(NSTEP-1) landed.
// EPI 0: LIF -> bitsT; EPI 1: mean/log_std heads; EPI 2: tanh action head.
// ---------------------------------------------------------------------------
template<int EPI>
__global__ __launch_bounds__(256)
void bitgemm(const unsigned* __restrict__ bitsT,
             const char* __restrict__ Wh,
             const char* __restrict__ Wl,
             const float* __restrict__ bias,
             const float* __restrict__ bias2,
             unsigned* __restrict__ obitsT,
             float* __restrict__ o0,
             float* __restrict__ o1) {
    __shared__ __align__(16) char smraw[34816];  // 4x8KB bufs | epi [4][32][66] f32
    const int tid = threadIdx.x;
    const int w = tid >> 6, l = tid & 63;
    const int kg = l >> 4, li = l & 15;
    const int nb = blockIdx.x, n0 = nb * 64;
    const int by = blockIdx.y;
    const int b = by * 4 + w;
    const unsigned fld = (kg & 1) * 16;

    i32x4 acc[2][4][2] = {};

    auto stage = [&](int s) {
        char* d = smraw + (s & 3) * 8192;
        const char* sH = Wh + (size_t)(nb * NSTEP + s) * 4096;
        const char* sL = Wl + (size_t)(nb * NSTEP + s) * 4096;
        gload_lds16(d + tid * 16, sH + tid * 16);
        gload_lds16(d + 4096 + tid * 16, sL + tid * 16);
    };
    auto loadA = [&](int s, unsigned (&aw)[2]) {
#pragma unroll
        for (int mt = 0; mt < 2; ++mt)
            aw[mt] = bitsT[((size_t)b * KW + s * 2 + (kg >> 1)) * TT + mt * 16 + li];
    };
    auto compute = [&](int s, const unsigned (&aw)[2]) {
        const char* bufB = smraw + (s & 3) * 8192;
        u32x4 afrag[2];
#pragma unroll
        for (int mt = 0; mt < 2; ++mt) {
            unsigned wv = aw[mt] >> fld;
            u32x4 a;
#pragma unroll
            for (int j = 0; j < 4; ++j)
                a[j] = __umul24((wv >> (4 * j)) & 0xFu, 0x00204081u) & 0x01010101u;
            afrag[mt] = a;
        }
        __builtin_amdgcn_s_setprio(1);
#pragma unroll
        for (int nt = 0; nt < 4; ++nt) {
            int boff = kg * 1024 + (nt * 16 + li) * 16;
            u32x4 bh = *(const u32x4*)(bufB + boff);
            u32x4 bl = *(const u32x4*)(bufB + 4096 + boff);
#pragma unroll
            for (int mt = 0; mt < 2; ++mt) {
                acc[mt][nt][0] = mfma_i8(afrag[mt], bh, acc[mt][nt][0]);
                acc[mt][nt][1] = mfma_i8(afrag[mt], bl, acc[mt][nt][1]);
            }
        }
        __builtin_amdgcn_s_setprio(0);
    };

    unsigned aw[2], awn[2];
    // order-robust prologue: buffer 0 is provably staged before the loop
    stage(0);
    asm volatile("s_waitcnt vmcnt(0)" ::: "memory");
    __builtin_amdgcn_s_barrier();
    stage(1);
    loadA(0, aw);

    for (int s = 0; s < NSTEP - 1; ++s) {
        asm volatile("s_waitcnt vmcnt(4)" ::: "memory");
        __builtin_amdgcn_s_barrier();
        __builtin_amdgcn_sched_barrier(0);
        if (s + 2 < NSTEP) stage(s + 2);
        loadA(s + 1, awn);
        compute(s, aw);
        aw[0] = awn[0];
        aw[1] = awn[1];
    }
    // peeled tail: pipeline is drained here (body NSTEP-2 issued only loadA),
    // so only a full drain proves stage(NSTEP-1) landed.
    asm volatile("s_waitcnt vmcnt(0)" ::: "memory");
    __builtin_amdgcn_s_barrier();
    __builtin_amdgcn_sched_barrier(0);
    compute(NSTEP - 1, aw);
    __syncthreads();   // slab aliases staging buffers

    // store C tile to wave-private slab [32][66]: row t = mt*16+kg*4+r, col nt*16+li
    float* Sf = (float*)smraw + (size_t)w * 32 * 66;
#pragma unroll
    for (int mt = 0; mt < 2; ++mt)
#pragma unroll
        for (int nt = 0; nt < 4; ++nt)
#pragma unroll
            for (int r = 0; r < 4; ++r) {
                int cmb = (acc[mt][nt][0][r] << 8) + acc[mt][nt][1][r];
                Sf[(mt * 16 + kg * 4 + r) * 66 + nt * 16 + li]
                    = (float)cmb * (1.f / 524288.f);
            }
    // wave-private: no barrier (in-wave DS ordering)

    // single pass: one column per lane (all 64 lanes active)
    int o = n0 + l;
    if (EPI == 0) {
        float bo = (o < HID) ? bias[o] : 0.f;
        float v = 0.f;
        unsigned sb = 0u;
#pragma unroll
        for (int t = 0; t < TT; ++t) {
            float h = 0.5f * (v + Sf[t * 66 + l] + bo);
            if (h >= 1.0f) { sb |= (1u << t); v = 0.f; }
            else           { v = h; }
        }
        if (o >= HID) sb = 0u;
        // full-wave ballot transpose: low 32 lanes -> kw even, high -> kw odd
        unsigned myw = 0;
#pragma unroll
        for (int t = 0; t < TT; ++t) {
            unsigned long long m = __ballot((sb >> t) & 1u);
            if ((l & 31) == t) myw = (l < 32) ? (unsigned)m : (unsigned)(m >> 32);
        }
        obitsT[((size_t)b * KW + nb * 2 + (l >= 32)) * TT + (l & 31)] = myw;
    } else {
        float mx = -1e30f;
#pragma unroll
        for (int t = 0; t < TT; ++t)
            mx = fmaxf(mx, Sf[t * 66 + l]);
        if (EPI == 1) {
            float bo = (o < LDIM) ? bias[o] : bias2[o - LDIM];
            float val = 0.5f * (mx + bo);
            if (o < LDIM) o0[(size_t)b * LDIM + o] = val;
            else          o1[(size_t)b * LDIM + (o - LDIM)] = val;
        } else {
            o0[(size_t)b * ADIM + l] = tanhf(0.5f * (mx + bias[l]));
        }
    }
}

// ---------------------------------------------------------------------------
extern "C" void kernel_launch(void* const* d_in, const int* in_sizes, int n_in,
                              void* d_out, int out_size, void* d_ws, size_t ws_size,
                              hipStream_t stream) {
    const float* state  = (const float*)d_in[0];
    const float* action = (const float*)d_in[1];
    const float* eps    = (const float*)d_in[2];
    const float* W1  = (const float*)d_in[3];
    const float* b1  = (const float*)d_in[4];
    const float* W2  = (const float*)d_in[5];
    const float* b2  = (const float*)d_in[6];
    const float* Wm  = (const float*)d_in[7];
    const float* bm  = (const float*)d_in[8];
    const float* Wls = (const float*)d_in[9];
    const float* bls = (const float*)d_in[10];
    const float* Wd1 = (const float*)d_in[11];
    const float* bd1 = (const float*)d_in[12];
    const float* Wd2 = (const float*)d_in[13];
    const float* bd2 = (const float*)d_in[14];
    const float* Wd3 = (const float*)d_in[15];
    const float* bd3 = (const float*)d_in[16];
    float* out = (float*)d_out;

    char* ws = (char*)d_ws;
    size_t off = 0;
    auto alloc = [&](size_t bytes) {
        void* p = ws + off;
        off += (bytes + 255) & ~(size_t)255;
        return p;
    };
    unsigned*       bitsT_a = (unsigned*)alloc((size_t)NB * TT * KW * 4);
    unsigned*       bitsT_b = (unsigned*)alloc((size_t)NB * TT * KW * 4);
    float*          mean_ws = (float*)   alloc((size_t)NB * LDIM * 4);
    float*          ls_ws   = (float*)   alloc((size_t)NB * LDIM * 4);
    unsigned short* Xh      = (unsigned short*)alloc((size_t)NB * DIN * 2);
    unsigned short* Xl      = (unsigned short*)alloc((size_t)NB * DIN * 2);
    char*           W2h     = (char*)alloc((size_t)KP * KP);
    char*           W2l     = (char*)alloc((size_t)KP * KP);
    char*           Wd2h    = (char*)alloc((size_t)KP * KP);
    char*           Wd2l    = (char*)alloc((size_t)KP * KP);
    char*           WmlsH   = (char*)alloc((size_t)256 * KP);
    char*           WmlsL   = (char*)alloc((size_t)256 * KP);
    char*           Wu3h    = (char*)alloc((size_t)64 * KP);
    char*           Wu3l    = (char*)alloc((size_t)64 * KP);
    unsigned short* W1h     = (unsigned short*)alloc((size_t)KP * EIN * 2);
    unsigned short* W1l     = (unsigned short*)alloc((size_t)KP * EIN * 2);
    unsigned short* Wd1h    = (unsigned short*)alloc((size_t)KP * DIN * 2);
    unsigned short* Wd1l    = (unsigned short*)alloc((size_t)KP * DIN * 2);

    dim3 blk(256);

    // weight prep (2 launches)
    wsplit_i8_all<<<(I8_E5 + 255) / 256, blk, 0, stream>>>(
        W2, Wd2, Wm, Wls, Wd3, W2h, W2l, Wd2h, Wd2l, WmlsH, WmlsL, Wu3h, Wu3l);
    wsplit_bf_all<<<(BF_E2 + 255) / 256, blk, 0, stream>>>(
        W1, Wd1, W1h, W1l, Wd1h, Wd1l);

    // encoder
    concat_xsplit_enc<<<(NB * (EIN / 8) + 255) / 256, blk, 0, stream>>>(state, action, Xh, Xl);
    lif1<5><<<dim3(12, 32), blk, 0, stream>>>(Xh, Xl, W1h, W1l, b1, bitsT_a);
    bitgemm<0><<<dim3(12, NB / 4), blk, 0, stream>>>(bitsT_a, W2h, W2l, b2, nullptr,
                                                     bitsT_b, nullptr, nullptr);
    bitgemm<1><<<dim3(4, NB / 4), blk, 0, stream>>>(bitsT_b, WmlsH, WmlsL, bm, bls,
                                                    nullptr, mean_ws, ls_ws);
    latent_xsplit<<<(NB * (DIN / 8) + 255) / 256, blk, 0, stream>>>(
        mean_ws, ls_ws, eps, state, out, Xh, Xl);

    // decoder
    lif1<6><<<dim3(12, 32), blk, 0, stream>>>(Xh, Xl, Wd1h, Wd1l, bd1, bitsT_a);
    bitgemm<0><<<dim3(12, NB / 4), blk, 0, stream>>>(bitsT_a, Wd2h, Wd2l, bd2, nullptr,
                                                     bitsT_b, nullptr, nullptr);
    bitgemm<2><<<dim3(1, NB / 4), blk, 0, stream>>>(bitsT_b, Wu3h, Wu3l, bd3, nullptr,
                                                    nullptr, out, nullptr);
}